// Round 11
// baseline (164.275 us; speedup 1.0000x reference)
//
#include <hip/hip_runtime.h>
#include <math.h>

#define B_   8
#define C_   512
#define N_   1024          // H*W
#define NH_  8
#define HC_  64

typedef __attribute__((ext_vector_type(8))) short bf16x8;
typedef __attribute__((ext_vector_type(4))) float f32x4;
typedef __attribute__((ext_vector_type(16))) float f32x16;

#define MFMA16(a, b, c) __builtin_amdgcn_mfma_f32_16x16x32_bf16(a, b, c, 0, 0, 0)
#define MFMA32(a, b, c) __builtin_amdgcn_mfma_f32_32x32x16_bf16(a, b, c, 0, 0, 0)

__device__ __forceinline__ unsigned short f2bf(float f) {
  unsigned u = __builtin_bit_cast(unsigned, f);
  u += 0x7fffu + ((u >> 16) & 1u);           // RNE
  return (unsigned short)(u >> 16);
}

__device__ __forceinline__ unsigned pack2(float a, float b) {
  return (unsigned)f2bf(a) | ((unsigned)f2bf(b) << 16);
}

// async global->LDS, 16B per lane; LDS dest is wave-uniform base + lane*16
__device__ __forceinline__ void gll16(const void* g, void* l) {
  __builtin_amdgcn_global_load_lds(
      (const __attribute__((address_space(1))) unsigned int*)g,
      (__attribute__((address_space(3))) unsigned int*)l, 16, 0, 0);
}

// ---------------------------------------------------------------------------
// prep: blocks 0..255 -> GroupNorm STATS ONLY (round 11: the normalize+write
// phase moved to prep2 — the old (b,g)-blocked writes were 16B scattered
// stores at 1KB pitch, max 32B per 128B line since a block owns 16/512
// channels). blocks 256..1279 -> weight conversion (unchanged).
// ---------------------------------------------------------------------------
__global__ __launch_bounds__(256) void prep(const float* __restrict__ x,
                                            const float* __restrict__ qkvw,
                                            const float* __restrict__ pw,
                                            float2* __restrict__ gstats,
                                            unsigned short* __restrict__ qkvw_bf,
                                            unsigned short* __restrict__ projw_bf) {
  const int t = threadIdx.x;
  if (blockIdx.x >= 256) {                   // weight conversion path
    const int widx = blockIdx.x - 256;
    const float* src = (widx < 768) ? qkvw : pw;
    unsigned short* dst = (widx < 768) ? qkvw_bf : projw_bf;
    const int i = ((widx < 768) ? widx : widx - 768) * 1024 + t * 4;
    const float4 v = *(const float4*)(src + i);
    ushort4 o;
    o.x = f2bf(v.x); o.y = f2bf(v.y); o.z = f2bf(v.z); o.w = f2bf(v.w);
    *(ushort4*)(dst + i) = o;
    return;
  }
  // ---- GroupNorm stats path: block = (b, g)
  const int b = blockIdx.x >> 5;
  const int g = blockIdx.x & 31;
  const float* xg = x + ((size_t)b * C_ + (size_t)g * 16) * N_;

  float s = 0.f, ss = 0.f;
#pragma unroll
  for (int k = 0; k < 16; ++k) {
    const float4 v = *(const float4*)(xg + (size_t)k * N_ + t * 4);
    s  += v.x + v.y + v.z + v.w;
    ss += v.x * v.x + v.y * v.y + v.z * v.z + v.w * v.w;
  }
#pragma unroll
  for (int off = 32; off > 0; off >>= 1) {
    s  += __shfl_down(s, off);
    ss += __shfl_down(ss, off);
  }
  __shared__ float rs[4], rss[4];
  if ((t & 63) == 0) { rs[t >> 6] = s; rss[t >> 6] = ss; }
  __syncthreads();
  if (t == 0) {
    s  = rs[0] + rs[1] + rs[2] + rs[3];
    ss = rss[0] + rss[1] + rss[2] + rss[3];
    const float mean = s * (1.f / 16384.f);
    const float var  = ss * (1.f / 16384.f) - mean * mean;
    gstats[b * 32 + g] = make_float2(mean, rsqrtf(var + 1e-5f));
  }
}

// ---------------------------------------------------------------------------
// prep2 (round 11): GroupNorm APPLY with coalesced transposed writes.
// Block = (b, 32-pixel tile); loops 4 chunks of 128 channels. x reads are
// full 128B lines (8 lanes x 16B per channel row); bf16 results transpose
// through an LDS tile [32px][pitch136] and store to hT as 256B-contiguous
// uint4 runs per pixel (vs old 32B scatter). Same arithmetic/order as the
// old prep write phase: (x*sc + of), sc = inv*gw, of = gb - mean*sc.
// ---------------------------------------------------------------------------
__global__ __launch_bounds__(256) void prep2(const float* __restrict__ x,
                                             const float* __restrict__ gw,
                                             const float* __restrict__ gb,
                                             const float2* __restrict__ gstats,
                                             unsigned short* __restrict__ hT) {
  __shared__ __attribute__((aligned(16))) short tile[32 * 136];
  const int t = threadIdx.x;
  const int b = blockIdx.x >> 5;             // 8 b x 32 tiles
  const int px0 = (blockIdx.x & 31) * 32;

  for (int chunk = 0; chunk < 4; ++chunk) {
    const int ch0 = chunk * 128;
    if (chunk) __syncthreads();              // WAR: prior readback done
#pragma unroll
    for (int it = 0; it < 4; ++it) {
      const int c = ch0 + (t >> 3) + it * 32;
      const int pxl = (t & 7) * 4;
      const float4 v = *(const float4*)(x + ((size_t)b * C_ + c) * N_ + px0 + pxl);
      const float2 mi = gstats[b * 32 + (c >> 4)];
      const float sc = mi.y * gw[c];
      const float of = gb[c] - mi.x * sc;
      tile[(pxl + 0) * 136 + (c - ch0)] = (short)f2bf(v.x * sc + of);
      tile[(pxl + 1) * 136 + (c - ch0)] = (short)f2bf(v.y * sc + of);
      tile[(pxl + 2) * 136 + (c - ch0)] = (short)f2bf(v.z * sc + of);
      tile[(pxl + 3) * 136 + (c - ch0)] = (short)f2bf(v.w * sc + of);
    }
    __syncthreads();                         // RAW: tile complete
#pragma unroll
    for (int u = 0; u < 2; ++u) {
      const int flat = u * 256 + t;
      const int cc8 = flat & 15, pxl = flat >> 4;
      *(uint4*)&hT[((size_t)b * N_ + px0 + pxl) * C_ + ch0 + cc8 * 8] =
          *(const uint4*)&tile[pxl * 136 + cc8 * 8];
    }
  }
}

// ---------------------------------------------------------------------------
// qkv GEMM: 128x128, BK=32, PEELED unconditional double-buffer (verified).
// K and V stored in attn FRAGMENT ORDER (kfrag/vfrag, verified round 9) so
// attn staging reads contiguous 1KB blocks. Q keeps old qkT layout.
// Q pre-scale folds log2(e) so attn softmax uses bare v_exp_f32 (2^x).
// ---------------------------------------------------------------------------
__global__ __launch_bounds__(256, 3) void gemm_qkv(
    const unsigned short* __restrict__ A, const float* __restrict__ bias,
    const unsigned short* __restrict__ BT, unsigned short* __restrict__ qkTout,
    unsigned short* __restrict__ kfrag, unsigned short* __restrict__ vfrag) {
  __shared__ __attribute__((aligned(16))) short lds[128 * 136];  // 34 KB
  const int t = threadIdx.x;
  const int lane = t & 63, w = t >> 6;
  const int lm = lane & 15, q = lane >> 4;
  const int wm = w >> 1, wn = w & 1;
  const int b = blockIdx.z;
  const int m0 = blockIdx.y * 128, n0 = blockIdx.x * 128;
  const unsigned short* Bb = BT + (size_t)b * N_ * C_;

  f32x4 acc[4][4];
#pragma unroll
  for (int i = 0; i < 4; ++i)
#pragma unroll
    for (int j = 0; j < 4; ++j) acc[i][j] = (f32x4){0.f, 0.f, 0.f, 0.f};

#define QKV_STAGE(k0, base_)                                                   \
  {                                                                            \
    _Pragma("unroll") for (int rr = 0; rr < 2; ++rr) {                         \
      const int rg = w * 2 + rr;                                               \
      gll16(A  + (size_t)(m0 + rg * 16 + lm) * C_ + (k0) + q * 8,              \
            (base_) + rg * 512);                                               \
      gll16(Bb + (size_t)(n0 + rg * 16 + lm) * C_ + (k0) + q * 8,              \
            (base_) + (8 + rg) * 512);                                         \
    }                                                                          \
  }

#define QKV_COMPUTE(base_)                                                     \
  {                                                                            \
    bf16x8 af[4];                                                              \
    _Pragma("unroll") for (int mi = 0; mi < 4; ++mi)                           \
      af[mi] = *(const bf16x8*)((base_) + (wm * 4 + mi) * 512 + lane * 8);     \
    _Pragma("unroll") for (int ni = 0; ni < 4; ++ni) {                         \
      const bf16x8 bfr =                                                       \
          *(const bf16x8*)((base_) + (8 + wn * 4 + ni) * 512 + lane * 8);      \
      _Pragma("unroll") for (int mi = 0; mi < 4; ++mi)                         \
        acc[mi][ni] = MFMA16(af[mi], bfr, acc[mi][ni]);                        \
    }                                                                          \
  }

  QKV_STAGE(0, lds)
  for (int it = 0; it < 15; ++it) {
    __syncthreads();   // drains prefetch issued LAST iter + WAR on bufs
    short* nxt = lds + ((it + 1) & 1) * 8192;
    QKV_STAGE((it + 1) * 32, nxt)          // unconditional prefetch
    const short* cur = lds + (it & 1) * 8192;
    QKV_COMPUTE(cur)
  }
  __syncthreads();
  QKV_COMPUTE(lds + 8192)                  // it = 15 -> buffer 1
#undef QKV_STAGE
#undef QKV_COMPUTE

  __syncthreads();  // staging dead before epilogue reuse
  if (blockIdx.y < 8) {
    // Q/K: transpose into LDS [p 128][o pitch136]
    // Q scale = hc^-0.5 * log2(e) so attn can use 2^x directly; K scale 1.
    const float qs = (blockIdx.y < 4) ? 0.18033688011112042f : 1.0f;
#pragma unroll
    for (int mi = 0; mi < 4; ++mi) {
#pragma unroll
      for (int ni = 0; ni < 4; ++ni) {
        const int pl = wn * 64 + ni * 16 + lm;
        const int ol0 = wm * 64 + mi * 16 + q * 4;
        ushort4 o4;
        o4.x = f2bf((acc[mi][ni][0] + bias[m0 + ol0 + 0]) * qs);
        o4.y = f2bf((acc[mi][ni][1] + bias[m0 + ol0 + 1]) * qs);
        o4.z = f2bf((acc[mi][ni][2] + bias[m0 + ol0 + 2]) * qs);
        o4.w = f2bf((acc[mi][ni][3] + bias[m0 + ol0 + 3]) * qs);
        *(ushort4*)&lds[pl * 136 + ol0] = o4;
      }
    }
    __syncthreads();
    if (blockIdx.y < 4) {
      // Q: old qkT layout [pixel][1024ch]
#pragma unroll
      for (int u = 0; u < 8; ++u) {
        const int flat = u * 256 + t;
        const int oc = flat & 15, pl = flat >> 4;
        *(uint4*)&qkTout[((size_t)b * N_ + n0 + pl) * 1024 + m0 + oc * 8] =
            *(const uint4*)&lds[pl * 136 + oc * 8];
      }
    } else {
      // K -> fragment order: kfrag[b][hh][jbg 32][kc 4][lane*8+e]
      const int hh0 = (blockIdx.y - 4) * 2;
#pragma unroll
      for (int u = 0; u < 8; ++u) {
        const int flat = u * 256 + t;
        const int ll = flat & 63, kc = (flat >> 6) & 3;
        const int jbl = (flat >> 8) & 3, hhl = flat >> 10;
        *(uint4*)&kfrag[((((size_t)b * 8 + hh0 + hhl) * 32 + (n0 >> 5) + jbl) * 4 +
                         kc) * 512 + ll * 8] =
            *(const uint4*)&lds[(jbl * 32 + (ll & 31)) * 136 + hhl * 64 +
                                kc * 16 + (ll >> 5) * 8];
      }
    }
  } else {
    // V: transpose into LDS [o 128][p pitch136]
#pragma unroll
    for (int mi = 0; mi < 4; ++mi)
#pragma unroll
      for (int ni = 0; ni < 4; ++ni) {
        const int pl = wn * 64 + ni * 16 + lm;
#pragma unroll
        for (int r = 0; r < 4; ++r) {
          const int ol = wm * 64 + mi * 16 + q * 4 + r;
          lds[ol * 136 + pl] = f2bf(acc[mi][ni][r] + bias[m0 + ol]);
        }
      }
    __syncthreads();
    // V -> fragment order: vfrag[b][hh][jt 16][nc 2][kj 4][lane*8+e]
    const int hh0 = (blockIdx.y - 8) * 2;
#pragma unroll
    for (int u = 0; u < 8; ++u) {
      const int flat = u * 256 + t;
      const int ll = flat & 63, kj = (flat >> 6) & 3;
      const int jtl = (flat >> 8) & 1, nc = (flat >> 9) & 1, hhl = flat >> 10;
      *(uint4*)&vfrag[(((((size_t)b * 8 + hh0 + hhl) * 16 + (n0 >> 6) + jtl) * 2 +
                        nc) * 4 + kj) * 512 + ll * 8] =
          *(const uint4*)&lds[(hhl * 64 + nc * 32 + (ll & 31)) * 136 +
                              jtl * 64 + kj * 16 + (ll >> 5) * 8];
    }
  }
}

// ---------------------------------------------------------------------------
// proj GEMM: 64x64 tile, BK=128 (4 k-iters), grid 1024 = 4 blocks/CU.
// ROUND 11: epilogue now bounces the 64x64 f32 tile through LDS (pitch 68)
// so the out stores and resid loads are float4 / 256B-contiguous per row
// (old: per-lane 4B stores at 4 rows x 1 col — 64B partial lines). FP order
// preserved: (acc + bias) at LDS-write, + resid at readback.
// ---------------------------------------------------------------------------
__global__ __launch_bounds__(256, 4) void gemm_proj(
    const unsigned short* __restrict__ A, const float* __restrict__ bias,
    const unsigned short* __restrict__ BT, const float* __restrict__ resid,
    float* __restrict__ outf) {
  __shared__ __attribute__((aligned(16))) short lds[32 * 512];  // A 0..15, B 16..31
  const int t = threadIdx.x;
  const int lane = t & 63, w = t >> 6;
  const int lm = lane & 15, q = lane >> 4;
  const int wm = w >> 1, wn = w & 1;
  const int b = blockIdx.z;
  const int m0 = blockIdx.y * 64, n0 = blockIdx.x * 64;
  const unsigned short* Bb = BT + (size_t)b * N_ * C_;

  f32x4 acc[2][2];
#pragma unroll
  for (int i = 0; i < 2; ++i)
#pragma unroll
    for (int j = 0; j < 2; ++j) acc[i][j] = (f32x4){0.f, 0.f, 0.f, 0.f};

  for (int k0 = 0; k0 < C_; k0 += 128) {
    __syncthreads();
#pragma unroll
    for (int ks = 0; ks < 4; ++ks) {
      gll16(A  + (size_t)(m0 + w * 16 + lm) * C_ + k0 + ks * 32 + q * 8,
            lds + (w * 4 + ks) * 512);
      gll16(Bb + (size_t)(n0 + w * 16 + lm) * C_ + k0 + ks * 32 + q * 8,
            lds + (16 + w * 4 + ks) * 512);
    }
    __syncthreads();
#pragma unroll
    for (int ks = 0; ks < 4; ++ks) {
      bf16x8 af[2];
#pragma unroll
      for (int mi = 0; mi < 2; ++mi)
        af[mi] = *(const bf16x8*)(lds + ((wm * 2 + mi) * 4 + ks) * 512 + lane * 8);
#pragma unroll
      for (int ni = 0; ni < 2; ++ni) {
        const bf16x8 bfr =
            *(const bf16x8*)(lds + (16 + (wn * 2 + ni) * 4 + ks) * 512 + lane * 8);
#pragma unroll
        for (int mi = 0; mi < 2; ++mi)
          acc[mi][ni] = MFMA16(af[mi], bfr, acc[mi][ni]);
      }
    }
  }

  // ---- coalesced epilogue via LDS f32 tile [64][pitch 68] (17.4 KB)
  __syncthreads();   // all compute reads of lds done before reuse
  float* fl = (float*)lds;
#pragma unroll
  for (int mi = 0; mi < 2; ++mi)
#pragma unroll
    for (int ni = 0; ni < 2; ++ni) {
      const int col_l = wn * 32 + ni * 16 + lm;
#pragma unroll
      for (int r = 0; r < 4; ++r) {
        const int row_l = wm * 32 + mi * 16 + q * 4 + r;
        fl[row_l * 68 + col_l] = acc[mi][ni][r] + bias[m0 + row_l];
      }
    }
  __syncthreads();
#pragma unroll
  for (int u = 0; u < 4; ++u) {
    const int flat = u * 256 + t;
    const int c4 = flat & 15, row_l = flat >> 4;
    const size_t oi = ((size_t)b * 512 + m0 + row_l) * N_ + n0 + c4 * 4;
    const float4 rv = *(const float4*)(resid + oi);
    const float4 av = *(const float4*)(fl + row_l * 68 + c4 * 4);
    float4 ov;
    ov.x = av.x + rv.x; ov.y = av.y + rv.y;
    ov.z = av.z + rv.z; ov.w = av.w + rv.w;
    *(float4*)(outf + oi) = ov;
  }
}

// ---------------------------------------------------------------------------
// Flash attention (round-9 verified BEST, verbatim): 32x32 MFMA, swapped
// QK^T, T12 in-reg softmax, frag-order contiguous gll16 staging, issue-early
// K dbuf / V single, 2 barriers/jt, XCD swizzle, setprio.
// ---------------------------------------------------------------------------
__global__ __launch_bounds__(256, 2) void attn_mfma(
    const unsigned short* __restrict__ qkT, const unsigned short* __restrict__ kfrag,
    const unsigned short* __restrict__ vfrag, unsigned short* __restrict__ aoT) {
  __shared__ __attribute__((aligned(16))) short lds[21504];  // 43008 B
  short* Ks = lds;               // 2 bufs x 8 frag-blocks x 512 shorts
  short* Vs = lds + 8192;        // 8 frag-blocks x 512 shorts
  short* Pb = lds + 12288;       // 4 waves x 2304 shorts (epilogue only)

  const int t = threadIdx.x;
  const int l = t & 63, w = t >> 6;
  const int l31 = l & 31, lh = l >> 5;
  const int id = blockIdx.x;
  const int xcd = id & 7, slot = id >> 3;
  const int pair = xcd * 8 + (slot >> 3);    // 0..63
  const int b = pair >> 3, hh = pair & 7;
  const int i0 = (slot & 7) * 128;

  const unsigned short* QT = qkT + (size_t)b * N_ * 1024;
  const unsigned short* kb = kfrag + (size_t)(b * 8 + hh) * 65536;
  const unsigned short* vb = vfrag + (size_t)(b * 8 + hh) * 65536;
  short* Pw = Pb + w * 2304;                 // wave-private epilogue buffer

  bf16x8 af[4];
#pragma unroll
  for (int kc = 0; kc < 4; ++kc)
    af[kc] = *(const bf16x8*)(QT + (size_t)(i0 + w * 32 + l31) * 1024 +
                              hh * 64 + kc * 16 + lh * 8);

  f32x16 accO[2];
#pragma unroll
  for (int r2 = 0; r2 < 16; ++r2) { accO[0][r2] = 0.f; accO[1][r2] = 0.f; }
  float lrun = 0.f;

#pragma unroll
  for (int rr = 0; rr < 2; ++rr) {
    const int idx = w * 2 + rr;
    gll16(kb + (size_t)idx * 512 + l * 8, Ks + idx * 512);
  }

  for (int jt = 0; jt < 16; ++jt) {
    __syncthreads();   // drains K(jt); WAR: PV(jt-1) Vs reads done
#pragma unroll
    for (int rr = 0; rr < 2; ++rr) {
      const int idx = w * 2 + rr;
      gll16(vb + ((size_t)jt * 8 + idx) * 512 + l * 8, Vs + idx * 512);
    }
    if (jt < 15) {
#pragma unroll
      for (int rr = 0; rr < 2; ++rr) {
        const int idx = w * 2 + rr;
        gll16(kb + ((size_t)(jt + 1) * 8 + idx) * 512 + l * 8,
              Ks + ((jt + 1) & 1) * 4096 + idx * 512);
      }
    }
    const short* Kc = Ks + (jt & 1) * 4096;

    f32x16 accS[2];
#pragma unroll
    for (int r2 = 0; r2 < 16; ++r2) { accS[0][r2] = 0.f; accS[1][r2] = 0.f; }
    __builtin_amdgcn_s_setprio(1);
#pragma unroll
    for (int kc = 0; kc < 4; ++kc)
#pragma unroll
      for (int jb = 0; jb < 2; ++jb) {
        const bf16x8 kfr = *(const bf16x8*)(Kc + (jb * 4 + kc) * 512 + l * 8);
        accS[jb] = MFMA32(kfr, af[kc], accS[jb]);
      }
    __builtin_amdgcn_s_setprio(0);

    uint4 pa4[4];
#pragma unroll
    for (int jb = 0; jb < 2; ++jb) {
      float p[16];
#pragma unroll
      for (int rg = 0; rg < 16; ++rg) {
        p[rg] = __builtin_exp2f(accS[jb][rg]);
        lrun += p[rg];
      }
      unsigned own[8];
#pragma unroll
      for (int i2 = 0; i2 < 8; ++i2)
        asm("v_cvt_pk_bf16_f32 %0, %1, %2"
            : "=v"(own[i2]) : "v"(p[2 * i2]), "v"(p[2 * i2 + 1]));
#pragma unroll
      for (int m = 0; m < 2; ++m) {
        unsigned x0 = own[4 * m + 0], y0 = own[4 * m + 2];
        unsigned x1 = own[4 * m + 1], y1 = own[4 * m + 3];
        asm("v_permlane32_swap_b32 %0, %1" : "+v"(x0), "+v"(y0));
        asm("v_permlane32_swap_b32 %0, %1" : "+v"(x1), "+v"(y1));
        pa4[jb * 2 + m] = (uint4){x0, x1, y0, y1};
      }
    }

    __syncthreads();   // drains V(jt) + K(jt+1) — mostly landed already

    __builtin_amdgcn_s_setprio(1);
#pragma unroll
    for (int kj = 0; kj < 4; ++kj) {
      const bf16x8 pf = __builtin_bit_cast(bf16x8, pa4[kj]);
#pragma unroll
      for (int nc = 0; nc < 2; ++nc) {
        const bf16x8 vf = *(const bf16x8*)(Vs + (nc * 4 + kj) * 512 + l * 8);
        accO[nc] = MFMA32(pf, vf, accO[nc]);
      }
    }
    __builtin_amdgcn_s_setprio(0);
  }

  const float lr = lrun + __shfl_xor(lrun, 32);
  float* lw = (float*)Pw;
  lw[l31] = 1.f / lr;
  float linvr[16];
#pragma unroll
  for (int rg = 0; rg < 16; ++rg)
    linvr[rg] = lw[(rg & 3) + ((rg >> 2) << 3) + (lh << 2)];

#pragma unroll
  for (int nc = 0; nc < 2; ++nc)
#pragma unroll
    for (int rg = 0; rg < 16; ++rg) {
      const int rowi = (rg & 3) + ((rg >> 2) << 3) + (lh << 2);
      Pw[rowi * 72 + nc * 32 + l31] = (short)f2bf(accO[nc][rg] * linvr[rg]);
    }
  unsigned short* aob = aoT + (size_t)b * N_ * C_;
#pragma unroll
  for (int u = 0; u < 4; ++u) {
    const int flat = u * 64 + l;
    const int c8 = flat & 7, row = flat >> 3;
    *(uint4*)&aob[(size_t)(i0 + w * 32 + row) * C_ + hh * 64 + c8 * 8] =
        *(const uint4*)&Pw[row * 72 + c8 * 8];
  }
}

// ---------------------------------------------------------------------------
// Launch
// ---------------------------------------------------------------------------
extern "C" void kernel_launch(void* const* d_in, const int* in_sizes, int n_in,
                              void* d_out, int out_size, void* d_ws, size_t ws_size,
                              hipStream_t stream) {
  const float* x    = (const float*)d_in[0];
  const float* gw   = (const float*)d_in[1];
  const float* gb   = (const float*)d_in[2];
  const float* qkvw = (const float*)d_in[3];
  const float* qkvb = (const float*)d_in[4];
  const float* pw   = (const float*)d_in[5];
  const float* pb   = (const float*)d_in[6];
  float* out = (float*)d_out;

  unsigned short* hT       = (unsigned short*)d_ws;
  unsigned short* qkvw_bf  = hT + (size_t)B_ * N_ * C_;
  unsigned short* projw_bf = qkvw_bf + 1536 * 512;
  unsigned short* qkT      = projw_bf + 512 * 512;
  unsigned short* aoTp     = qkT + (size_t)B_ * N_ * 1024;
  unsigned short* kfrag    = aoTp + (size_t)B_ * N_ * C_;
  unsigned short* vfrag    = kfrag + (size_t)64 * 65536;
  float2* gstats           = (float2*)(vfrag + (size_t)64 * 65536);

  prep<<<1280, 256, 0, stream>>>(x, qkvw, pw, gstats, qkvw_bf, projw_bf);
  prep2<<<256, 256, 0, stream>>>(x, gw, gb, gstats, hT);
  gemm_qkv<<<dim3(8, 12, B_), 256, 0, stream>>>(qkvw_bf, qkvb, hT, qkT, kfrag, vfrag);
  attn_mfma<<<512, 256, 0, stream>>>(qkT, kfrag, vfrag, aoTp);
  gemm_proj<<<dim3(16, 8, B_), 256, 0, stream>>>(projw_bf, pb, aoTp, x, out);
}

// Round 12
// 161.063 us; speedup vs baseline: 1.0199x; 1.0199x over previous
//
#include <hip/hip_runtime.h>
#include <math.h>

#define B_   8
#define C_   512
#define N_   1024          // H*W
#define NH_  8
#define HC_  64

typedef __attribute__((ext_vector_type(8))) short bf16x8;
typedef __attribute__((ext_vector_type(4))) float f32x4;
typedef __attribute__((ext_vector_type(16))) float f32x16;

#define MFMA16(a, b, c) __builtin_amdgcn_mfma_f32_16x16x32_bf16(a, b, c, 0, 0, 0)
#define MFMA32(a, b, c) __builtin_amdgcn_mfma_f32_32x32x16_bf16(a, b, c, 0, 0, 0)

__device__ __forceinline__ unsigned short f2bf(float f) {
  unsigned u = __builtin_bit_cast(unsigned, f);
  u += 0x7fffu + ((u >> 16) & 1u);           // RNE
  return (unsigned short)(u >> 16);
}

__device__ __forceinline__ unsigned pack2(float a, float b) {
  return (unsigned)f2bf(a) | ((unsigned)f2bf(b) << 16);
}

// async global->LDS, 16B per lane; LDS dest is wave-uniform base + lane*16
__device__ __forceinline__ void gll16(const void* g, void* l) {
  __builtin_amdgcn_global_load_lds(
      (const __attribute__((address_space(1))) unsigned int*)g,
      (__attribute__((address_space(3))) unsigned int*)l, 16, 0, 0);
}

// ---------------------------------------------------------------------------
// prep (round-9 verified, single-pass): blocks 0..255 -> fused GroupNorm
// (x read ONCE, kept in registers); blocks 256..1279 -> weight convert.
// r11's stats/apply split cost an extra 16MB x read + a launch — reverted.
// ---------------------------------------------------------------------------
__global__ __launch_bounds__(256) void prep(const float* __restrict__ x,
                                            const float* __restrict__ gw,
                                            const float* __restrict__ gb,
                                            const float* __restrict__ qkvw,
                                            const float* __restrict__ pw,
                                            unsigned short* __restrict__ hT,
                                            unsigned short* __restrict__ qkvw_bf,
                                            unsigned short* __restrict__ projw_bf) {
  const int t = threadIdx.x;
  if (blockIdx.x >= 256) {                   // weight conversion path
    const int widx = blockIdx.x - 256;
    const float* src = (widx < 768) ? qkvw : pw;
    unsigned short* dst = (widx < 768) ? qkvw_bf : projw_bf;
    const int i = ((widx < 768) ? widx : widx - 768) * 1024 + t * 4;
    const float4 v = *(const float4*)(src + i);
    ushort4 o;
    o.x = f2bf(v.x); o.y = f2bf(v.y); o.z = f2bf(v.z); o.w = f2bf(v.w);
    *(ushort4*)(dst + i) = o;
    return;
  }
  // ---- GroupNorm path: block = (b, g)
  const int b = blockIdx.x >> 5;
  const int g = blockIdx.x & 31;
  const float* xg = x + ((size_t)b * C_ + (size_t)g * 16) * N_;

  float4 xv[16];                             // channel k, pixels 4t..4t+3
  float s = 0.f, ss = 0.f;
#pragma unroll
  for (int k = 0; k < 16; ++k) {
    xv[k] = *(const float4*)(xg + (size_t)k * N_ + t * 4);
    s  += xv[k].x + xv[k].y + xv[k].z + xv[k].w;
    ss += xv[k].x * xv[k].x + xv[k].y * xv[k].y + xv[k].z * xv[k].z + xv[k].w * xv[k].w;
  }
#pragma unroll
  for (int off = 32; off > 0; off >>= 1) {
    s  += __shfl_down(s, off);
    ss += __shfl_down(ss, off);
  }
  __shared__ float rs[4], rss[4], sh_mi[2];
  if ((t & 63) == 0) { rs[t >> 6] = s; rss[t >> 6] = ss; }
  __syncthreads();
  if (t == 0) {
    s  = rs[0] + rs[1] + rs[2] + rs[3];
    ss = rss[0] + rss[1] + rss[2] + rss[3];
    const float mean = s * (1.f / 16384.f);
    const float var  = ss * (1.f / 16384.f) - mean * mean;
    sh_mi[0] = mean;
    sh_mi[1] = rsqrtf(var + 1e-5f);
  }
  __syncthreads();
  const float mean = sh_mi[0], inv = sh_mi[1];

  float sc[16], of[16];
#pragma unroll
  for (int k = 0; k < 16; ++k) {
    const int c = g * 16 + k;
    sc[k] = inv * gw[c];
    of[k] = gb[c] - mean * sc[k];
  }
#pragma unroll
  for (int r = 0; r < 4; ++r) {
    const int p = t * 4 + r;
    unsigned short* dst = hT + ((size_t)b * N_ + p) * C_ + g * 16;
    uint4 o0, o1;
#pragma unroll
    for (int k2 = 0; k2 < 4; ++k2) {
      const float a0 = ((const float*)&xv[k2 * 2 + 0])[r] * sc[k2 * 2 + 0] + of[k2 * 2 + 0];
      const float a1 = ((const float*)&xv[k2 * 2 + 1])[r] * sc[k2 * 2 + 1] + of[k2 * 2 + 1];
      ((unsigned*)&o0)[k2] = pack2(a0, a1);
      const float b0 = ((const float*)&xv[8 + k2 * 2 + 0])[r] * sc[8 + k2 * 2 + 0] + of[8 + k2 * 2 + 0];
      const float b1 = ((const float*)&xv[8 + k2 * 2 + 1])[r] * sc[8 + k2 * 2 + 1] + of[8 + k2 * 2 + 1];
      ((unsigned*)&o1)[k2] = pack2(b0, b1);
    }
    *(uint4*)(dst)     = o0;
    *(uint4*)(dst + 8) = o1;
  }
}

// ---------------------------------------------------------------------------
// qkv GEMM: 128x128, BK=32, PEELED unconditional double-buffer (verified).
// K and V stored in attn FRAGMENT ORDER (kfrag/vfrag, verified round 9) so
// attn staging reads contiguous 1KB blocks. Q keeps old qkT layout.
// Q pre-scale folds log2(e) so attn softmax uses bare v_exp_f32 (2^x).
// ---------------------------------------------------------------------------
__global__ __launch_bounds__(256, 3) void gemm_qkv(
    const unsigned short* __restrict__ A, const float* __restrict__ bias,
    const unsigned short* __restrict__ BT, unsigned short* __restrict__ qkTout,
    unsigned short* __restrict__ kfrag, unsigned short* __restrict__ vfrag) {
  __shared__ __attribute__((aligned(16))) short lds[128 * 136];  // 34 KB
  const int t = threadIdx.x;
  const int lane = t & 63, w = t >> 6;
  const int lm = lane & 15, q = lane >> 4;
  const int wm = w >> 1, wn = w & 1;
  const int b = blockIdx.z;
  const int m0 = blockIdx.y * 128, n0 = blockIdx.x * 128;
  const unsigned short* Bb = BT + (size_t)b * N_ * C_;

  f32x4 acc[4][4];
#pragma unroll
  for (int i = 0; i < 4; ++i)
#pragma unroll
    for (int j = 0; j < 4; ++j) acc[i][j] = (f32x4){0.f, 0.f, 0.f, 0.f};

#define QKV_STAGE(k0, base_)                                                   \
  {                                                                            \
    _Pragma("unroll") for (int rr = 0; rr < 2; ++rr) {                         \
      const int rg = w * 2 + rr;                                               \
      gll16(A  + (size_t)(m0 + rg * 16 + lm) * C_ + (k0) + q * 8,              \
            (base_) + rg * 512);                                               \
      gll16(Bb + (size_t)(n0 + rg * 16 + lm) * C_ + (k0) + q * 8,              \
            (base_) + (8 + rg) * 512);                                         \
    }                                                                          \
  }

#define QKV_COMPUTE(base_)                                                     \
  {                                                                            \
    bf16x8 af[4];                                                              \
    _Pragma("unroll") for (int mi = 0; mi < 4; ++mi)                           \
      af[mi] = *(const bf16x8*)((base_) + (wm * 4 + mi) * 512 + lane * 8);     \
    _Pragma("unroll") for (int ni = 0; ni < 4; ++ni) {                         \
      const bf16x8 bfr =                                                       \
          *(const bf16x8*)((base_) + (8 + wn * 4 + ni) * 512 + lane * 8);      \
      _Pragma("unroll") for (int mi = 0; mi < 4; ++mi)                         \
        acc[mi][ni] = MFMA16(af[mi], bfr, acc[mi][ni]);                        \
    }                                                                          \
  }

  QKV_STAGE(0, lds)
  for (int it = 0; it < 15; ++it) {
    __syncthreads();   // drains prefetch issued LAST iter + WAR on bufs
    short* nxt = lds + ((it + 1) & 1) * 8192;
    QKV_STAGE((it + 1) * 32, nxt)          // unconditional prefetch
    const short* cur = lds + (it & 1) * 8192;
    QKV_COMPUTE(cur)
  }
  __syncthreads();
  QKV_COMPUTE(lds + 8192)                  // it = 15 -> buffer 1
#undef QKV_STAGE
#undef QKV_COMPUTE

  __syncthreads();  // staging dead before epilogue reuse
  if (blockIdx.y < 8) {
    // Q/K: transpose into LDS [p 128][o pitch136]
    // Q scale = hc^-0.5 * log2(e) so attn can use 2^x directly; K scale 1.
    const float qs = (blockIdx.y < 4) ? 0.18033688011112042f : 1.0f;
#pragma unroll
    for (int mi = 0; mi < 4; ++mi) {
#pragma unroll
      for (int ni = 0; ni < 4; ++ni) {
        const int pl = wn * 64 + ni * 16 + lm;
        const int ol0 = wm * 64 + mi * 16 + q * 4;
        ushort4 o4;
        o4.x = f2bf((acc[mi][ni][0] + bias[m0 + ol0 + 0]) * qs);
        o4.y = f2bf((acc[mi][ni][1] + bias[m0 + ol0 + 1]) * qs);
        o4.z = f2bf((acc[mi][ni][2] + bias[m0 + ol0 + 2]) * qs);
        o4.w = f2bf((acc[mi][ni][3] + bias[m0 + ol0 + 3]) * qs);
        *(ushort4*)&lds[pl * 136 + ol0] = o4;
      }
    }
    __syncthreads();
    if (blockIdx.y < 4) {
      // Q: old qkT layout [pixel][1024ch]
#pragma unroll
      for (int u = 0; u < 8; ++u) {
        const int flat = u * 256 + t;
        const int oc = flat & 15, pl = flat >> 4;
        *(uint4*)&qkTout[((size_t)b * N_ + n0 + pl) * 1024 + m0 + oc * 8] =
            *(const uint4*)&lds[pl * 136 + oc * 8];
      }
    } else {
      // K -> fragment order: kfrag[b][hh][jbg 32][kc 4][lane*8+e]
      const int hh0 = (blockIdx.y - 4) * 2;
#pragma unroll
      for (int u = 0; u < 8; ++u) {
        const int flat = u * 256 + t;
        const int ll = flat & 63, kc = (flat >> 6) & 3;
        const int jbl = (flat >> 8) & 3, hhl = flat >> 10;
        *(uint4*)&kfrag[((((size_t)b * 8 + hh0 + hhl) * 32 + (n0 >> 5) + jbl) * 4 +
                         kc) * 512 + ll * 8] =
            *(const uint4*)&lds[(jbl * 32 + (ll & 31)) * 136 + hhl * 64 +
                                kc * 16 + (ll >> 5) * 8];
      }
    }
  } else {
    // V: transpose into LDS [o 128][p pitch136]
#pragma unroll
    for (int mi = 0; mi < 4; ++mi)
#pragma unroll
      for (int ni = 0; ni < 4; ++ni) {
        const int pl = wn * 64 + ni * 16 + lm;
#pragma unroll
        for (int r = 0; r < 4; ++r) {
          const int ol = wm * 64 + mi * 16 + q * 4 + r;
          lds[ol * 136 + pl] = f2bf(acc[mi][ni][r] + bias[m0 + ol]);
        }
      }
    __syncthreads();
    // V -> fragment order: vfrag[b][hh][jt 16][nc 2][kj 4][lane*8+e]
    const int hh0 = (blockIdx.y - 8) * 2;
#pragma unroll
    for (int u = 0; u < 8; ++u) {
      const int flat = u * 256 + t;
      const int ll = flat & 63, kj = (flat >> 6) & 3;
      const int jtl = (flat >> 8) & 1, nc = (flat >> 9) & 1, hhl = flat >> 10;
      *(uint4*)&vfrag[(((((size_t)b * 8 + hh0 + hhl) * 16 + (n0 >> 6) + jtl) * 2 +
                        nc) * 4 + kj) * 512 + ll * 8] =
          *(const uint4*)&lds[(hhl * 64 + nc * 32 + (ll & 31)) * 136 +
                              jtl * 64 + kj * 16 + (ll >> 5) * 8];
    }
  }
}

// ---------------------------------------------------------------------------
// proj GEMM: 64x64 tile, BK=128 (4 k-iters), grid 1024 = 4 blocks/CU.
// ROUND 12 (single-variable A/B vs r9): LDS f32 epilogue (pitch 68) —
// float4 / 256B-contiguous out stores + resid loads (old: per-lane 4B
// stores, 4 rows x 1 col). Harness-verified correct in r11 (same absmax).
// FP order preserved: (acc + bias) at LDS-write, + resid at readback.
// ---------------------------------------------------------------------------
__global__ __launch_bounds__(256, 4) void gemm_proj(
    const unsigned short* __restrict__ A, const float* __restrict__ bias,
    const unsigned short* __restrict__ BT, const float* __restrict__ resid,
    float* __restrict__ outf) {
  __shared__ __attribute__((aligned(16))) short lds[32 * 512];  // A 0..15, B 16..31
  const int t = threadIdx.x;
  const int lane = t & 63, w = t >> 6;
  const int lm = lane & 15, q = lane >> 4;
  const int wm = w >> 1, wn = w & 1;
  const int b = blockIdx.z;
  const int m0 = blockIdx.y * 64, n0 = blockIdx.x * 64;
  const unsigned short* Bb = BT + (size_t)b * N_ * C_;

  f32x4 acc[2][2];
#pragma unroll
  for (int i = 0; i < 2; ++i)
#pragma unroll
    for (int j = 0; j < 2; ++j) acc[i][j] = (f32x4){0.f, 0.f, 0.f, 0.f};

  for (int k0 = 0; k0 < C_; k0 += 128) {
    __syncthreads();
#pragma unroll
    for (int ks = 0; ks < 4; ++ks) {
      gll16(A  + (size_t)(m0 + w * 16 + lm) * C_ + k0 + ks * 32 + q * 8,
            lds + (w * 4 + ks) * 512);
      gll16(Bb + (size_t)(n0 + w * 16 + lm) * C_ + k0 + ks * 32 + q * 8,
            lds + (16 + w * 4 + ks) * 512);
    }
    __syncthreads();
#pragma unroll
    for (int ks = 0; ks < 4; ++ks) {
      bf16x8 af[2];
#pragma unroll
      for (int mi = 0; mi < 2; ++mi)
        af[mi] = *(const bf16x8*)(lds + ((wm * 2 + mi) * 4 + ks) * 512 + lane * 8);
#pragma unroll
      for (int ni = 0; ni < 2; ++ni) {
        const bf16x8 bfr =
            *(const bf16x8*)(lds + (16 + (wn * 2 + ni) * 4 + ks) * 512 + lane * 8);
#pragma unroll
        for (int mi = 0; mi < 2; ++mi)
          acc[mi][ni] = MFMA16(af[mi], bfr, acc[mi][ni]);
      }
    }
  }

  // ---- coalesced epilogue via LDS f32 tile [64][pitch 68] (17.4 KB)
  __syncthreads();   // all compute reads of lds done before reuse
  float* fl = (float*)lds;
#pragma unroll
  for (int mi = 0; mi < 2; ++mi)
#pragma unroll
    for (int ni = 0; ni < 2; ++ni) {
      const int col_l = wn * 32 + ni * 16 + lm;
#pragma unroll
      for (int r = 0; r < 4; ++r) {
        const int row_l = wm * 32 + mi * 16 + q * 4 + r;
        fl[row_l * 68 + col_l] = acc[mi][ni][r] + bias[m0 + row_l];
      }
    }
  __syncthreads();
#pragma unroll
  for (int u = 0; u < 4; ++u) {
    const int flat = u * 256 + t;
    const int c4 = flat & 15, row_l = flat >> 4;
    const size_t oi = ((size_t)b * 512 + m0 + row_l) * N_ + n0 + c4 * 4;
    const float4 rv = *(const float4*)(resid + oi);
    const float4 av = *(const float4*)(fl + row_l * 68 + c4 * 4);
    float4 ov;
    ov.x = av.x + rv.x; ov.y = av.y + rv.y;
    ov.z = av.z + rv.z; ov.w = av.w + rv.w;
    *(float4*)(outf + oi) = ov;
  }
}

// ---------------------------------------------------------------------------
// Flash attention (round-9 verified BEST, verbatim): 32x32 MFMA, swapped
// QK^T, T12 in-reg softmax, frag-order contiguous gll16 staging, issue-early
// K dbuf / V single, 2 barriers/jt, XCD swizzle, setprio.
// ---------------------------------------------------------------------------
__global__ __launch_bounds__(256, 2) void attn_mfma(
    const unsigned short* __restrict__ qkT, const unsigned short* __restrict__ kfrag,
    const unsigned short* __restrict__ vfrag, unsigned short* __restrict__ aoT) {
  __shared__ __attribute__((aligned(16))) short lds[21504];  // 43008 B
  short* Ks = lds;               // 2 bufs x 8 frag-blocks x 512 shorts
  short* Vs = lds + 8192;        // 8 frag-blocks x 512 shorts
  short* Pb = lds + 12288;       // 4 waves x 2304 shorts (epilogue only)

  const int t = threadIdx.x;
  const int l = t & 63, w = t >> 6;
  const int l31 = l & 31, lh = l >> 5;
  const int id = blockIdx.x;
  const int xcd = id & 7, slot = id >> 3;
  const int pair = xcd * 8 + (slot >> 3);    // 0..63
  const int b = pair >> 3, hh = pair & 7;
  const int i0 = (slot & 7) * 128;

  const unsigned short* QT = qkT + (size_t)b * N_ * 1024;
  const unsigned short* kb = kfrag + (size_t)(b * 8 + hh) * 65536;
  const unsigned short* vb = vfrag + (size_t)(b * 8 + hh) * 65536;
  short* Pw = Pb + w * 2304;                 // wave-private epilogue buffer

  bf16x8 af[4];
#pragma unroll
  for (int kc = 0; kc < 4; ++kc)
    af[kc] = *(const bf16x8*)(QT + (size_t)(i0 + w * 32 + l31) * 1024 +
                              hh * 64 + kc * 16 + lh * 8);

  f32x16 accO[2];
#pragma unroll
  for (int r2 = 0; r2 < 16; ++r2) { accO[0][r2] = 0.f; accO[1][r2] = 0.f; }
  float lrun = 0.f;

#pragma unroll
  for (int rr = 0; rr < 2; ++rr) {
    const int idx = w * 2 + rr;
    gll16(kb + (size_t)idx * 512 + l * 8, Ks + idx * 512);
  }

  for (int jt = 0; jt < 16; ++jt) {
    __syncthreads();   // drains K(jt); WAR: PV(jt-1) Vs reads done
#pragma unroll
    for (int rr = 0; rr < 2; ++rr) {
      const int idx = w * 2 + rr;
      gll16(vb + ((size_t)jt * 8 + idx) * 512 + l * 8, Vs + idx * 512);
    }
    if (jt < 15) {
#pragma unroll
      for (int rr = 0; rr < 2; ++rr) {
        const int idx = w * 2 + rr;
        gll16(kb + ((size_t)(jt + 1) * 8 + idx) * 512 + l * 8,
              Ks + ((jt + 1) & 1) * 4096 + idx * 512);
      }
    }
    const short* Kc = Ks + (jt & 1) * 4096;

    f32x16 accS[2];
#pragma unroll
    for (int r2 = 0; r2 < 16; ++r2) { accS[0][r2] = 0.f; accS[1][r2] = 0.f; }
    __builtin_amdgcn_s_setprio(1);
#pragma unroll
    for (int kc = 0; kc < 4; ++kc)
#pragma unroll
      for (int jb = 0; jb < 2; ++jb) {
        const bf16x8 kfr = *(const bf16x8*)(Kc + (jb * 4 + kc) * 512 + l * 8);
        accS[jb] = MFMA32(kfr, af[kc], accS[jb]);
      }
    __builtin_amdgcn_s_setprio(0);

    uint4 pa4[4];
#pragma unroll
    for (int jb = 0; jb < 2; ++jb) {
      float p[16];
#pragma unroll
      for (int rg = 0; rg < 16; ++rg) {
        p[rg] = __builtin_exp2f(accS[jb][rg]);
        lrun += p[rg];
      }
      unsigned own[8];
#pragma unroll
      for (int i2 = 0; i2 < 8; ++i2)
        asm("v_cvt_pk_bf16_f32 %0, %1, %2"
            : "=v"(own[i2]) : "v"(p[2 * i2]), "v"(p[2 * i2 + 1]));
#pragma unroll
      for (int m = 0; m < 2; ++m) {
        unsigned x0 = own[4 * m + 0], y0 = own[4 * m + 2];
        unsigned x1 = own[4 * m + 1], y1 = own[4 * m + 3];
        asm("v_permlane32_swap_b32 %0, %1" : "+v"(x0), "+v"(y0));
        asm("v_permlane32_swap_b32 %0, %1" : "+v"(x1), "+v"(y1));
        pa4[jb * 2 + m] = (uint4){x0, x1, y0, y1};
      }
    }

    __syncthreads();   // drains V(jt) + K(jt+1) — mostly landed already

    __builtin_amdgcn_s_setprio(1);
#pragma unroll
    for (int kj = 0; kj < 4; ++kj) {
      const bf16x8 pf = __builtin_bit_cast(bf16x8, pa4[kj]);
#pragma unroll
      for (int nc = 0; nc < 2; ++nc) {
        const bf16x8 vf = *(const bf16x8*)(Vs + (nc * 4 + kj) * 512 + l * 8);
        accO[nc] = MFMA32(pf, vf, accO[nc]);
      }
    }
    __builtin_amdgcn_s_setprio(0);
  }

  const float lr = lrun + __shfl_xor(lrun, 32);
  float* lw = (float*)Pw;
  lw[l31] = 1.f / lr;
  float linvr[16];
#pragma unroll
  for (int rg = 0; rg < 16; ++rg)
    linvr[rg] = lw[(rg & 3) + ((rg >> 2) << 3) + (lh << 2)];

#pragma unroll
  for (int nc = 0; nc < 2; ++nc)
#pragma unroll
    for (int rg = 0; rg < 16; ++rg) {
      const int rowi = (rg & 3) + ((rg >> 2) << 3) + (lh << 2);
      Pw[rowi * 72 + nc * 32 + l31] = (short)f2bf(accO[nc][rg] * linvr[rg]);
    }
  unsigned short* aob = aoT + (size_t)b * N_ * C_;
#pragma unroll
  for (int u = 0; u < 4; ++u) {
    const int flat = u * 64 + l;
    const int c8 = flat & 7, row = flat >> 3;
    *(uint4*)&aob[(size_t)(i0 + w * 32 + row) * C_ + hh * 64 + c8 * 8] =
        *(const uint4*)&Pw[row * 72 + c8 * 8];
  }
}

// ---------------------------------------------------------------------------
// Launch
// ---------------------------------------------------------------------------
extern "C" void kernel_launch(void* const* d_in, const int* in_sizes, int n_in,
                              void* d_out, int out_size, void* d_ws, size_t ws_size,
                              hipStream_t stream) {
  const float* x    = (const float*)d_in[0];
  const float* gw   = (const float*)d_in[1];
  const float* gb   = (const float*)d_in[2];
  const float* qkvw = (const float*)d_in[3];
  const float* qkvb = (const float*)d_in[4];
  const float* pw   = (const float*)d_in[5];
  const float* pb   = (const float*)d_in[6];
  float* out = (float*)d_out;

  unsigned short* hT       = (unsigned short*)d_ws;
  unsigned short* qkvw_bf  = hT + (size_t)B_ * N_ * C_;
  unsigned short* projw_bf = qkvw_bf + 1536 * 512;
  unsigned short* qkT      = projw_bf + 512 * 512;
  unsigned short* aoTp     = qkT + (size_t)B_ * N_ * 1024;
  unsigned short* kfrag    = aoTp + (size_t)B_ * N_ * C_;
  unsigned short* vfrag    = kfrag + (size_t)64 * 65536;

  prep<<<1280, 256, 0, stream>>>(x, gw, gb, qkvw, pw, hT, qkvw_bf, projw_bf);
  gemm_qkv<<<dim3(8, 12, B_), 256, 0, stream>>>(qkvw_bf, qkvb, hT, qkT, kfrag, vfrag);
  attn_mfma<<<512, 256, 0, stream>>>(qkT, kfrag, vfrag, aoTp);
  gemm_proj<<<dim3(16, 8, B_), 256, 0, stream>>>(projw_bf, pb, aoTp, x, out);
}